// Round 2
// baseline (533.042 us; speedup 1.0000x reference)
//
#include <hip/hip_runtime.h>
#include <math.h>

#define F_DIM 49
#define T_DIM 25
#define O_CH  16
#define G_CH  4
#define OG    64
#define T_IN  8000
#define B_SZ  64
#define TILE  128          // output taus per block
#define EXT   160          // padded yf extent (152 used = TILE + T_DIM - 1)
#define XSW   168          // xs row stride (dwords)
#define YFW   176          // yfs row stride (dwords); phys col max = 159+16 = 175

// ---------------- prep: build separable kernel factors ----------------
// Kf[f][og] = exp(-0.5*((f-mu_f)/sig_f)^2)                  (49 x 64)
// Kt[og][t] = exp(-0.5*((t-mu_t)/sig_t)^2) * W/(Sf*St+1e-7) (64 x 25)
__global__ void strf_prep(const float* __restrict__ W,
                          const float* __restrict__ P,
                          const float* __restrict__ SIG,
                          float* __restrict__ Kf,
                          float* __restrict__ Kt)
{
    int og = threadIdx.x;
    if (og >= OG) return;
    float mu_f = P[og]      + (float)(F_DIM / 2);
    float mu_t = P[OG + og] + (float)(T_DIM / 2);
    float sf = fabsf(SIG[og])      + 0.27f;
    float st = fabsf(SIG[OG + og]) + 0.27f;

    float xf[F_DIM];
    float Sf = 0.0f;
#pragma unroll
    for (int f = 0; f < F_DIM; ++f) {
        float d = ((float)f - mu_f) / sf;
        float e = expf(-0.5f * d * d);
        xf[f] = e;
        Sf += e;
    }
    float xt[T_DIM];
    float St = 0.0f;
#pragma unroll
    for (int t = 0; t < T_DIM; ++t) {
        float d = ((float)t - mu_t) / st;
        float e = expf(-0.5f * d * d);
        xt[t] = e;
        St += e;
    }
    float scale = W[og] / (Sf * St + 1e-7f);
#pragma unroll
    for (int f = 0; f < F_DIM; ++f) Kf[f * OG + og] = xf[f];
#pragma unroll
    for (int t = 0; t < T_DIM; ++t) Kt[og * T_DIM + t] = xt[t] * scale;
}

// ---------------- main fused separable conv ----------------
// Per block: one batch b, one time tile of TILE outputs.
// Phase 0: stage x[b, :, t0-24 .. t0+135] into LDS (zero-padded).
// Phase 1: yfs[og][c] = sum_f Kf[f][og] * xs[f][c]     (8og x 5tau per thread)
// Phase 2: out[b,o,t0+u] = sum_g sum_t Kt[og][t] * yfs[og][u+t]
__global__ __launch_bounds__(256, 2)
void strf_main(const float* __restrict__ x,
               const float* __restrict__ Kf,
               const float* __restrict__ Kt,
               float* __restrict__ out)
{
    __shared__ __align__(16) float xs[F_DIM * XSW];
    __shared__ __align__(16) float yfs[OG * YFW];

    const int tid  = threadIdx.x;
    const int tile = blockIdx.x;
    const int b    = blockIdx.y;
    const int t0   = tile * TILE;

    // ---- phase 0: load x tile ----
    const float* xb = x + (size_t)b * (F_DIM * T_IN);
    for (int idx = tid; idx < F_DIM * EXT; idx += 256) {
        int f = idx / EXT;
        int c = idx - f * EXT;
        int tg = t0 - (T_DIM - 1) + c;
        float v = (tg >= 0 && tg < T_IN) ? xb[f * T_IN + tg] : 0.0f;
        xs[f * XSW + c] = v;
    }
    __syncthreads();

    // ---- phase 1: frequency reduction ----
    {
        const int og0  = (tid >> 5) * 8;   // lanes 0-31 share og0 -> Kf loads broadcast
        const int tg   = tid & 31;
        const int tau0 = tg * 5;           // stride-5 dwords -> conflict-free xs reads

        float acc[8][5];
#pragma unroll
        for (int i = 0; i < 8; ++i)
#pragma unroll
            for (int j = 0; j < 5; ++j) acc[i][j] = 0.0f;

        const float* kfp = Kf + og0;
        const float* xsp = xs + tau0;
        for (int f = 0; f < F_DIM; ++f) {
            float xv[5];
#pragma unroll
            for (int j = 0; j < 5; ++j) xv[j] = xsp[j];
            xsp += XSW;
            float4 k0 = *(const float4*)(kfp);
            float4 k1 = *(const float4*)(kfp + 4);
            kfp += OG;
            float kf[8] = {k0.x, k0.y, k0.z, k0.w, k1.x, k1.y, k1.z, k1.w};
#pragma unroll
            for (int i = 0; i < 8; ++i)
#pragma unroll
                for (int j = 0; j < 5; ++j)
                    acc[i][j] = fmaf(kf[i], xv[j], acc[i][j]);
        }
        // write with additive column stagger: pc = c + 4*(c>>5)
#pragma unroll
        for (int i = 0; i < 8; ++i) {
            float* row = yfs + (og0 + i) * YFW;
#pragma unroll
            for (int j = 0; j < 5; ++j) {
                int c  = tau0 + j;
                int pc = c + ((c >> 5) << 2);
                row[pc] = acc[i][j];
            }
        }
    }
    __syncthreads();

    // ---- phase 2: 25-tap causal time conv + g-sum ----
    {
        const int o    = tid >> 4;         // lanes 0-15 share o -> Kt loads broadcast
        const int tg   = tid & 15;
        const int tau0 = tg * 8;

        float acc[8];
#pragma unroll
        for (int j = 0; j < 8; ++j) acc[j] = 0.0f;

        for (int g = 0; g < G_CH; ++g) {
            const int og = o * G_CH + g;
            float kt[T_DIM];
            const float* ktp = Kt + og * T_DIM;
#pragma unroll
            for (int t = 0; t < T_DIM; ++t) kt[t] = ktp[t];

            // register window: logical cols tau0 .. tau0+31
            float w[32];
            const float* row = yfs + og * YFW;
#pragma unroll
            for (int ch = 0; ch < 8; ++ch) {
                int c  = tau0 + ch * 4;
                int pc = c + ((c >> 5) << 2);    // chunk stays contiguous & 16B-aligned
                float4 v = *(const float4*)(row + pc);
                w[ch * 4 + 0] = v.x;
                w[ch * 4 + 1] = v.y;
                w[ch * 4 + 2] = v.z;
                w[ch * 4 + 3] = v.w;
            }
#pragma unroll
            for (int t = 0; t < T_DIM; ++t)
#pragma unroll
                for (int j = 0; j < 8; ++j)
                    acc[j] = fmaf(kt[t], w[t + j], acc[j]);
        }

        const int taug = t0 + tau0;
        if (taug + 7 < T_IN) {             // 8000 % 8 == 0 -> chunks all-or-nothing
            float* op = out + ((size_t)b * O_CH + o) * T_IN + taug;
            *(float4*)op       = make_float4(acc[0], acc[1], acc[2], acc[3]);
            *(float4*)(op + 4) = make_float4(acc[4], acc[5], acc[6], acc[7]);
        }
    }
}

extern "C" void kernel_launch(void* const* d_in, const int* in_sizes, int n_in,
                              void* d_out, int out_size, void* d_ws, size_t ws_size,
                              hipStream_t stream) {
    const float* x   = (const float*)d_in[0];
    const float* W   = (const float*)d_in[1];
    const float* P   = (const float*)d_in[2];
    const float* SIG = (const float*)d_in[3];
    float* outp = (float*)d_out;

    float* Kf = (float*)d_ws;            // 49*64 floats
    float* Kt = Kf + F_DIM * OG;         // 64*25 floats

    strf_prep<<<dim3(1), dim3(64), 0, stream>>>(W, P, SIG, Kf, Kt);

    dim3 grid((T_IN + TILE - 1) / TILE, B_SZ);
    strf_main<<<grid, dim3(256), 0, stream>>>(x, Kf, Kt, outp);
}

// Round 3
// 297.478 us; speedup vs baseline: 1.7919x; 1.7919x over previous
//
#include <hip/hip_runtime.h>
#include <math.h>

#define F_DIM 49
#define T_DIM 25
#define O_CH  16
#define G_CH  4
#define OG    64
#define T_IN  8000
#define B_SZ  64
#define NCHUNK (T_IN / 16)        // 500 chunks of 16 taus (8000 % 16 == 0)

// ---------------- prep: build separable kernel factors ----------------
// Kf[f][og] = exp(-0.5*((f-mu_f)/sig_f)^2)                  (49 x 64)
// Kt[og][t] = exp(-0.5*((t-mu_t)/sig_t)^2) * W/(Sf*St+1e-7) (64 x 25)
__global__ void strf_prep(const float* __restrict__ W,
                          const float* __restrict__ P,
                          const float* __restrict__ SIG,
                          float* __restrict__ Kf,
                          float* __restrict__ Kt)
{
    int og = threadIdx.x;
    if (og >= OG) return;
    float mu_f = P[og]      + (float)(F_DIM / 2);
    float mu_t = P[OG + og] + (float)(T_DIM / 2);
    float sf = fabsf(SIG[og])      + 0.27f;
    float st = fabsf(SIG[OG + og]) + 0.27f;

    float xf[F_DIM];
    float Sf = 0.0f;
#pragma unroll
    for (int f = 0; f < F_DIM; ++f) {
        float d = ((float)f - mu_f) / sf;
        float e = expf(-0.5f * d * d);
        xf[f] = e;
        Sf += e;
    }
    float xt[T_DIM];
    float St = 0.0f;
#pragma unroll
    for (int t = 0; t < T_DIM; ++t) {
        float d = ((float)t - mu_t) / st;
        float e = expf(-0.5f * d * d);
        xt[t] = e;
        St += e;
    }
    float scale = W[og] / (Sf * St + 1e-7f);
#pragma unroll
    for (int f = 0; f < F_DIM; ++f) Kf[f * OG + og] = xf[f];
#pragma unroll
    for (int t = 0; t < T_DIM; ++t) Kt[og * T_DIM + t] = xt[t] * scale;
}

// ---------------- kernel 1: frequency reduction (streaming) ----------------
// yf[bl][og][tau] = sum_f Kf[f][og] * x[b0+bl][f][tau]
// thread = one tau; 64 fp32 accumulators; Kf loads wave-uniform (scalar);
// x loads coalesced dwords. No LDS, no barriers.
__global__ __launch_bounds__(256)
void strf_freq(const float* __restrict__ x,
               const float* __restrict__ Kf,
               float* __restrict__ yf,
               int b0)
{
    const int tau = blockIdx.x * 256 + threadIdx.x;
    const int bl  = blockIdx.y;                 // slice-local batch
    const bool ok = tau < T_IN;
    const int tc  = ok ? tau : (T_IN - 1);
    const float* xp = x + (size_t)(b0 + bl) * (F_DIM * T_IN) + tc;

    float acc[OG];
#pragma unroll
    for (int og = 0; og < OG; ++og) acc[og] = 0.0f;

    for (int f = 0; f < F_DIM; ++f) {
        float xv = xp[(size_t)f * T_IN];
        const float* kf = Kf + f * OG;          // uniform address -> s_load
#pragma unroll
        for (int og = 0; og < OG; ++og)
            acc[og] = fmaf(kf[og], xv, acc[og]);
    }

    if (ok) {
        float* yp = yf + (size_t)bl * (OG * T_IN) + tau;
#pragma unroll
        for (int og = 0; og < OG; ++og)
            yp[(size_t)og * T_IN] = acc[og];
    }
}

// ---------------- kernel 2: 25-tap causal time conv + g-sum ----------------
// out[b0+bl][o][tau0..tau0+15] = sum_g sum_t Kt[o*4+g][t] * yf[bl][o*4+g][tau0-24+t+j]
// thread = 16 taus; window + taps fully static (registers). No LDS, no barriers.
__global__ __launch_bounds__(256)
void strf_time(const float* __restrict__ yf,
               const float* __restrict__ Kt,
               float* __restrict__ out,
               int b0)
{
    const int c = blockIdx.x * 256 + threadIdx.x;
    if (c >= NCHUNK) return;
    const int o    = blockIdx.y;
    const int bl   = blockIdx.z;
    const int tau0 = c * 16;

    float acc[16];
#pragma unroll
    for (int j = 0; j < 16; ++j) acc[j] = 0.0f;

    for (int g = 0; g < G_CH; ++g) {
        const int og = o * G_CH + g;
        const float* yp  = yf + ((size_t)bl * OG + og) * T_IN;
        const float* ktp = Kt + og * T_DIM;     // uniform -> s_load
        float kt[T_DIM];
#pragma unroll
        for (int t = 0; t < T_DIM; ++t) kt[t] = ktp[t];

        float w[40];                            // taus tau0-24 .. tau0+15
        if (c >= 2) {
            const float* base = yp + tau0 - 24; // multiple of 8 -> 16B aligned
#pragma unroll
            for (int j = 0; j < 10; ++j) {
                float4 v = *(const float4*)(base + 4 * j);
                w[4 * j + 0] = v.x; w[4 * j + 1] = v.y;
                w[4 * j + 2] = v.z; w[4 * j + 3] = v.w;
            }
        } else {
#pragma unroll
            for (int m = 0; m < 40; ++m) {
                int t = tau0 - 24 + m;
                w[m] = (t >= 0) ? yp[t] : 0.0f; // causal zero pad
            }
        }
#pragma unroll
        for (int t = 0; t < T_DIM; ++t)
#pragma unroll
            for (int j = 0; j < 16; ++j)
                acc[j] = fmaf(kt[t], w[t + j], acc[j]);
    }

    float* op = out + ((size_t)(b0 + bl) * O_CH + o) * T_IN + tau0;
#pragma unroll
    for (int j = 0; j < 4; ++j)
        *(float4*)(op + 4 * j) =
            make_float4(acc[4 * j], acc[4 * j + 1], acc[4 * j + 2], acc[4 * j + 3]);
}

// ---------------- fallback: round-2 fused kernel (proven correct) ----------------
#define TILE  128
#define EXT   160
#define XSW   168
#define YFW   176

__global__ __launch_bounds__(256, 2)
void strf_main(const float* __restrict__ x,
               const float* __restrict__ Kf,
               const float* __restrict__ Kt,
               float* __restrict__ out)
{
    __shared__ __align__(16) float xs[F_DIM * XSW];
    __shared__ __align__(16) float yfs[OG * YFW];

    const int tid  = threadIdx.x;
    const int tile = blockIdx.x;
    const int b    = blockIdx.y;
    const int t0   = tile * TILE;

    const float* xb = x + (size_t)b * (F_DIM * T_IN);
    for (int idx = tid; idx < F_DIM * EXT; idx += 256) {
        int f = idx / EXT;
        int c = idx - f * EXT;
        int tg = t0 - (T_DIM - 1) + c;
        float v = (tg >= 0 && tg < T_IN) ? xb[f * T_IN + tg] : 0.0f;
        xs[f * XSW + c] = v;
    }
    __syncthreads();

    {
        const int og0  = (tid >> 5) * 8;
        const int tg   = tid & 31;
        const int tau0 = tg * 5;

        float acc[8][5];
#pragma unroll
        for (int i = 0; i < 8; ++i)
#pragma unroll
            for (int j = 0; j < 5; ++j) acc[i][j] = 0.0f;

        const float* kfp = Kf + og0;
        const float* xsp = xs + tau0;
        for (int f = 0; f < F_DIM; ++f) {
            float xv[5];
#pragma unroll
            for (int j = 0; j < 5; ++j) xv[j] = xsp[j];
            xsp += XSW;
            float4 k0 = *(const float4*)(kfp);
            float4 k1 = *(const float4*)(kfp + 4);
            kfp += OG;
            float kf[8] = {k0.x, k0.y, k0.z, k0.w, k1.x, k1.y, k1.z, k1.w};
#pragma unroll
            for (int i = 0; i < 8; ++i)
#pragma unroll
                for (int j = 0; j < 5; ++j)
                    acc[i][j] = fmaf(kf[i], xv[j], acc[i][j]);
        }
#pragma unroll
        for (int i = 0; i < 8; ++i) {
            float* row = yfs + (og0 + i) * YFW;
#pragma unroll
            for (int j = 0; j < 5; ++j) {
                int c  = tau0 + j;
                int pc = c + ((c >> 5) << 2);
                row[pc] = acc[i][j];
            }
        }
    }
    __syncthreads();

    {
        const int o    = tid >> 4;
        const int tg   = tid & 15;
        const int tau0 = tg * 8;

        float acc[8];
#pragma unroll
        for (int j = 0; j < 8; ++j) acc[j] = 0.0f;

        for (int g = 0; g < G_CH; ++g) {
            const int og = o * G_CH + g;
            float kt[T_DIM];
            const float* ktp = Kt + og * T_DIM;
#pragma unroll
            for (int t = 0; t < T_DIM; ++t) kt[t] = ktp[t];

            float w[32];
            const float* row = yfs + og * YFW;
#pragma unroll
            for (int ch = 0; ch < 8; ++ch) {
                int c  = tau0 + ch * 4;
                int pc = c + ((c >> 5) << 2);
                float4 v = *(const float4*)(row + pc);
                w[ch * 4 + 0] = v.x;
                w[ch * 4 + 1] = v.y;
                w[ch * 4 + 2] = v.z;
                w[ch * 4 + 3] = v.w;
            }
#pragma unroll
            for (int t = 0; t < T_DIM; ++t)
#pragma unroll
                for (int j = 0; j < 8; ++j)
                    acc[j] = fmaf(kt[t], w[t + j], acc[j]);
        }

        const int taug = t0 + tau0;
        if (taug + 7 < T_IN) {
            float* op = out + ((size_t)b * O_CH + o) * T_IN + taug;
            *(float4*)op       = make_float4(acc[0], acc[1], acc[2], acc[3]);
            *(float4*)(op + 4) = make_float4(acc[4], acc[5], acc[6], acc[7]);
        }
    }
}

extern "C" void kernel_launch(void* const* d_in, const int* in_sizes, int n_in,
                              void* d_out, int out_size, void* d_ws, size_t ws_size,
                              hipStream_t stream) {
    const float* x   = (const float*)d_in[0];
    const float* W   = (const float*)d_in[1];
    const float* P   = (const float*)d_in[2];
    const float* SIG = (const float*)d_in[3];
    float* outp = (float*)d_out;

    float* Kf = (float*)d_ws;                    // 49*64 floats
    float* Kt = Kf + F_DIM * OG;                 // 64*25 floats

    strf_prep<<<dim3(1), dim3(64), 0, stream>>>(W, P, SIG, Kf, Kt);

    // yf intermediate lives at a 32 KiB offset into d_ws
    const size_t yf_off_b  = 32768;
    const size_t per_b     = (size_t)OG * T_IN * sizeof(float);   // 2.048 MB / batch
    const size_t avail     = (ws_size > yf_off_b) ? (ws_size - yf_off_b) : 0;
    const int    max_nb    = (int)(avail / per_b);

    if (max_nb >= 8) {
        float* yfp = (float*)((char*)d_ws + yf_off_b);
        for (int b0 = 0; b0 < B_SZ; ) {
            int nb = B_SZ - b0;
            if (nb > max_nb) nb = max_nb;
            strf_freq<<<dim3((T_IN + 255) / 256, nb), dim3(256), 0, stream>>>(x, Kf, yfp, b0);
            strf_time<<<dim3((NCHUNK + 255) / 256, O_CH, nb), dim3(256), 0, stream>>>(yfp, Kt, outp, b0);
            b0 += nb;
        }
    } else {
        // workspace too small for the split path: proven fused fallback
        dim3 grid((T_IN + TILE - 1) / TILE, B_SZ);
        strf_main<<<grid, dim3(256), 0, stream>>>(x, Kf, Kt, outp);
    }
}

// Round 8
// 250.043 us; speedup vs baseline: 2.1318x; 1.1897x over previous
//
#include <hip/hip_runtime.h>
#include <math.h>

#define F_DIM 49
#define T_DIM 25
#define O_CH  16
#define G_CH  4
#define OG    64
#define T_IN  8000
#define B_SZ  64

// ---------------- prep: build separable kernel factors ----------------
// Kf[f][og] = exp(-0.5*((f-mu_f)/sig_f)^2)                  (49 x 64)
// Kt[og][t] = exp(-0.5*((t-mu_t)/sig_t)^2) * W/(Sf*St+1e-7) (64 x 25)
__global__ void strf_prep(const float* __restrict__ W,
                          const float* __restrict__ P,
                          const float* __restrict__ SIG,
                          float* __restrict__ Kf,
                          float* __restrict__ Kt)
{
    int og = threadIdx.x;
    if (og >= OG) return;
    float mu_f = P[og]      + (float)(F_DIM / 2);
    float mu_t = P[OG + og] + (float)(T_DIM / 2);
    float sf = fabsf(SIG[og])      + 0.27f;
    float st = fabsf(SIG[OG + og]) + 0.27f;

    float xf[F_DIM];
    float Sf = 0.0f;
#pragma unroll
    for (int f = 0; f < F_DIM; ++f) {
        float d = ((float)f - mu_f) / sf;
        float e = expf(-0.5f * d * d);
        xf[f] = e;
        Sf += e;
    }
    float xt[T_DIM];
    float St = 0.0f;
#pragma unroll
    for (int t = 0; t < T_DIM; ++t) {
        float d = ((float)t - mu_t) / st;
        float e = expf(-0.5f * d * d);
        xt[t] = e;
        St += e;
    }
    float scale = W[og] / (Sf * St + 1e-7f);
#pragma unroll
    for (int f = 0; f < F_DIM; ++f) Kf[f * OG + og] = xf[f];
#pragma unroll
    for (int t = 0; t < T_DIM; ++t) Kt[og * T_DIM + t] = xt[t] * scale;
}

// ---------------- kernel 1: frequency reduction (streaming, float4) --------
// yf[bl][og][tau] = sum_f Kf[f][og] * x[b0+bl][f][tau]
// thread = 4 taus (float4) x 16 og. og-group comes from blockIdx.z so all
// Kf addresses are dispatch-uniform (scalar). Software-pipelined x loads.
__global__ __launch_bounds__(256)
void strf_freq(const float* __restrict__ x,
               const float* __restrict__ Kf,
               float* __restrict__ yf,
               int b0)
{
    const int chunk = blockIdx.x * 256 + threadIdx.x;   // tau/4 chunk, 2000 per row
    const int bl    = blockIdx.y;
    const int og0   = blockIdx.z * 16;
    if (chunk >= T_IN / 4) return;
    const int tau0 = chunk * 4;

    const float* xp = x + (size_t)(b0 + bl) * (F_DIM * T_IN) + tau0;

    float acc[16][4];
#pragma unroll
    for (int i = 0; i < 16; ++i)
#pragma unroll
        for (int j = 0; j < 4; ++j) acc[i][j] = 0.0f;

    float4 cur = *(const float4*)xp;
#pragma unroll 2
    for (int f = 0; f < F_DIM - 1; ++f) {
        float4 nxt = *(const float4*)(xp + (size_t)(f + 1) * T_IN);
        const float* kfp = Kf + f * OG + og0;
        float4 k0 = *(const float4*)(kfp);
        float4 k1 = *(const float4*)(kfp + 4);
        float4 k2 = *(const float4*)(kfp + 8);
        float4 k3 = *(const float4*)(kfp + 12);
        float kv[16] = {k0.x, k0.y, k0.z, k0.w, k1.x, k1.y, k1.z, k1.w,
                        k2.x, k2.y, k2.z, k2.w, k3.x, k3.y, k3.z, k3.w};
        float cv[4] = {cur.x, cur.y, cur.z, cur.w};
#pragma unroll
        for (int i = 0; i < 16; ++i)
#pragma unroll
            for (int j = 0; j < 4; ++j)
                acc[i][j] = fmaf(kv[i], cv[j], acc[i][j]);
        cur = nxt;
    }
    {   // peeled last tap
        const float* kfp = Kf + (F_DIM - 1) * OG + og0;
        float4 k0 = *(const float4*)(kfp);
        float4 k1 = *(const float4*)(kfp + 4);
        float4 k2 = *(const float4*)(kfp + 8);
        float4 k3 = *(const float4*)(kfp + 12);
        float kv[16] = {k0.x, k0.y, k0.z, k0.w, k1.x, k1.y, k1.z, k1.w,
                        k2.x, k2.y, k2.z, k2.w, k3.x, k3.y, k3.z, k3.w};
        float cv[4] = {cur.x, cur.y, cur.z, cur.w};
#pragma unroll
        for (int i = 0; i < 16; ++i)
#pragma unroll
            for (int j = 0; j < 4; ++j)
                acc[i][j] = fmaf(kv[i], cv[j], acc[i][j]);
    }

    float* yp = yf + ((size_t)bl * OG + og0) * T_IN + tau0;
#pragma unroll
    for (int i = 0; i < 16; ++i)
        *(float4*)(yp + (size_t)i * T_IN) =
            make_float4(acc[i][0], acc[i][1], acc[i][2], acc[i][3]);
}

// ---------------- kernel 2: 25-tap causal time conv + g-sum ----------------
// thread = 8 taus; window = 8 aligned float4 loads (lane stride 32B).
// yf is L3-resident from pass 1.
__global__ __launch_bounds__(256)
void strf_time(const float* __restrict__ yf,
               const float* __restrict__ Kt,
               float* __restrict__ out,
               int b0)
{
    const int chunk = blockIdx.x * 256 + threadIdx.x;   // tau/8 chunk, 1000 per row
    if (chunk >= T_IN / 8) return;
    const int o    = blockIdx.y;
    const int bl   = blockIdx.z;
    const int tau0 = chunk * 8;

    float acc[8];
#pragma unroll
    for (int j = 0; j < 8; ++j) acc[j] = 0.0f;

#pragma unroll
    for (int g = 0; g < G_CH; ++g) {
        const int og = o * G_CH + g;
        const float* ktp = Kt + og * T_DIM;     // dispatch-uniform -> s_load
        float kt[T_DIM];
#pragma unroll
        for (int t = 0; t < T_DIM; ++t) kt[t] = ktp[t];

        const float* yp = yf + ((size_t)bl * OG + og) * T_IN;
        float w[32];                            // taus tau0-24 .. tau0+7
        if (tau0 >= 24) {
            const float* base = yp + tau0 - 24; // multiple of 4 -> 16B aligned
#pragma unroll
            for (int j = 0; j < 8; ++j) {
                float4 v = *(const float4*)(base + 4 * j);
                w[4 * j + 0] = v.x; w[4 * j + 1] = v.y;
                w[4 * j + 2] = v.z; w[4 * j + 3] = v.w;
            }
        } else {
#pragma unroll
            for (int m = 0; m < 32; ++m) {
                int t = tau0 - 24 + m;
                w[m] = (t >= 0) ? yp[t] : 0.0f; // causal zero pad
            }
        }
#pragma unroll
        for (int t = 0; t < T_DIM; ++t)
#pragma unroll
            for (int j = 0; j < 8; ++j)
                acc[j] = fmaf(kt[t], w[t + j], acc[j]);
    }

    float* op = out + ((size_t)(b0 + bl) * O_CH + o) * T_IN + tau0;
    *(float4*)op       = make_float4(acc[0], acc[1], acc[2], acc[3]);
    *(float4*)(op + 4) = make_float4(acc[4], acc[5], acc[6], acc[7]);
}

// ---------------- fallback: round-2 fused kernel (proven correct) ----------
#define TILE  128
#define EXT   160
#define XSW   168
#define YFW   176

__global__ __launch_bounds__(256, 2)
void strf_main(const float* __restrict__ x,
               const float* __restrict__ Kf,
               const float* __restrict__ Kt,
               float* __restrict__ out)
{
    __shared__ __align__(16) float xs[F_DIM * XSW];
    __shared__ __align__(16) float yfs[OG * YFW];

    const int tid  = threadIdx.x;
    const int tile = blockIdx.x;
    const int b    = blockIdx.y;
    const int t0   = tile * TILE;

    const float* xb = x + (size_t)b * (F_DIM * T_IN);
    for (int idx = tid; idx < F_DIM * EXT; idx += 256) {
        int f = idx / EXT;
        int c = idx - f * EXT;
        int tg = t0 - (T_DIM - 1) + c;
        float v = (tg >= 0 && tg < T_IN) ? xb[f * T_IN + tg] : 0.0f;
        xs[f * XSW + c] = v;
    }
    __syncthreads();

    {
        const int og0  = (tid >> 5) * 8;
        const int tg   = tid & 31;
        const int tau0 = tg * 5;

        float acc[8][5];
#pragma unroll
        for (int i = 0; i < 8; ++i)
#pragma unroll
            for (int j = 0; j < 5; ++j) acc[i][j] = 0.0f;

        const float* kfp = Kf + og0;
        const float* xsp = xs + tau0;
        for (int f = 0; f < F_DIM; ++f) {
            float xv[5];
#pragma unroll
            for (int j = 0; j < 5; ++j) xv[j] = xsp[j];
            xsp += XSW;
            float4 k0 = *(const float4*)(kfp);
            float4 k1 = *(const float4*)(kfp + 4);
            kfp += OG;
            float kf[8] = {k0.x, k0.y, k0.z, k0.w, k1.x, k1.y, k1.z, k1.w};
#pragma unroll
            for (int i = 0; i < 8; ++i)
#pragma unroll
                for (int j = 0; j < 5; ++j)
                    acc[i][j] = fmaf(kf[i], xv[j], acc[i][j]);
        }
#pragma unroll
        for (int i = 0; i < 8; ++i) {
            float* row = yfs + (og0 + i) * YFW;
#pragma unroll
            for (int j = 0; j < 5; ++j) {
                int c  = tau0 + j;
                int pc = c + ((c >> 5) << 2);
                row[pc] = acc[i][j];
            }
        }
    }
    __syncthreads();

    {
        const int o    = tid >> 4;
        const int tg   = tid & 15;
        const int tau0 = tg * 8;

        float acc[8];
#pragma unroll
        for (int j = 0; j < 8; ++j) acc[j] = 0.0f;

        for (int g = 0; g < G_CH; ++g) {
            const int og = o * G_CH + g;
            float kt[T_DIM];
            const float* ktp = Kt + og * T_DIM;
#pragma unroll
            for (int t = 0; t < T_DIM; ++t) kt[t] = ktp[t];

            float w[32];
            const float* row = yfs + og * YFW;
#pragma unroll
            for (int ch = 0; ch < 8; ++ch) {
                int c  = tau0 + ch * 4;
                int pc = c + ((c >> 5) << 2);
                float4 v = *(const float4*)(row + pc);
                w[ch * 4 + 0] = v.x;
                w[ch * 4 + 1] = v.y;
                w[ch * 4 + 2] = v.z;
                w[ch * 4 + 3] = v.w;
            }
#pragma unroll
            for (int t = 0; t < T_DIM; ++t)
#pragma unroll
                for (int j = 0; j < 8; ++j)
                    acc[j] = fmaf(kt[t], w[t + j], acc[j]);
        }

        const int taug = t0 + tau0;
        if (taug + 7 < T_IN) {
            float* op = out + ((size_t)b * O_CH + o) * T_IN + taug;
            *(float4*)op       = make_float4(acc[0], acc[1], acc[2], acc[3]);
            *(float4*)(op + 4) = make_float4(acc[4], acc[5], acc[6], acc[7]);
        }
    }
}

extern "C" void kernel_launch(void* const* d_in, const int* in_sizes, int n_in,
                              void* d_out, int out_size, void* d_ws, size_t ws_size,
                              hipStream_t stream) {
    const float* x   = (const float*)d_in[0];
    const float* W   = (const float*)d_in[1];
    const float* P   = (const float*)d_in[2];
    const float* SIG = (const float*)d_in[3];
    float* outp = (float*)d_out;

    float* Kf = (float*)d_ws;                    // 49*64 floats
    float* Kt = Kf + F_DIM * OG;                 // 64*25 floats

    strf_prep<<<dim3(1), dim3(64), 0, stream>>>(W, P, SIG, Kf, Kt);

    const size_t yf_off_b  = 32768;
    const size_t per_b     = (size_t)OG * T_IN * sizeof(float);   // 2.048 MB / batch
    const size_t avail     = (ws_size > yf_off_b) ? (ws_size - yf_off_b) : 0;
    const int    max_nb    = (int)(avail / per_b);

    if (max_nb >= 8) {
        float* yfp = (float*)((char*)d_ws + yf_off_b);
        for (int b0 = 0; b0 < B_SZ; ) {
            int nb = B_SZ - b0;
            if (nb > max_nb) nb = max_nb;
            // freq: 2000 tau-chunks (of 4) per (b,og-group)
            strf_freq<<<dim3((T_IN / 4 + 255) / 256, nb, G_CH),
                        dim3(256), 0, stream>>>(x, Kf, yfp, b0);
            // time: 1000 tau-chunks (of 8) per (b,o)
            strf_time<<<dim3((T_IN / 8 + 255) / 256, O_CH, nb),
                        dim3(256), 0, stream>>>(yfp, Kt, outp, b0);
            b0 += nb;
        }
    } else {
        dim3 grid((T_IN + TILE - 1) / TILE, B_SZ);
        strf_main<<<grid, dim3(256), 0, stream>>>(x, Kf, Kt, outp);
    }
}

// Round 12
// 235.844 us; speedup vs baseline: 2.2601x; 1.0602x over previous
//
#include <hip/hip_runtime.h>
#include <math.h>

#define F_DIM 49
#define T_DIM 25
#define O_CH  16
#define G_CH  4
#define OG    64
#define T_IN  8000
#define B_SZ  64
#define SEG   2000         // taus per strf_time2 block
#define HALO  24
#define LW    (SEG + HALO) // 2024 staged bf16 per og row
#define LSTR  2032         // LDS row stride (ushort), mult of 8 -> 16B-aligned rows

typedef unsigned int  uint32;
typedef unsigned short ushort16;

__device__ __forceinline__ ushort16 f2bf(float x) {
    uint32 u = __float_as_uint(x);
    u = (u + 0x7fffu + ((u >> 16) & 1u)) >> 16;   // RNE
    return (ushort16)u;
}
__device__ __forceinline__ float bf2f(ushort16 h) {
    return __uint_as_float(((uint32)h) << 16);
}

// ---------------- prep: build separable kernel factors ----------------
// Kf[f][og] = exp(-0.5*((f-mu_f)/sig_f)^2)                  (49 x 64)
// Kt[og][t] = exp(-0.5*((t-mu_t)/sig_t)^2) * W/(Sf*St+1e-7) (64 x 25)
__global__ void strf_prep(const float* __restrict__ W,
                          const float* __restrict__ P,
                          const float* __restrict__ SIG,
                          float* __restrict__ Kf,
                          float* __restrict__ Kt)
{
    int og = threadIdx.x;
    if (og >= OG) return;
    float mu_f = P[og]      + (float)(F_DIM / 2);
    float mu_t = P[OG + og] + (float)(T_DIM / 2);
    float sf = fabsf(SIG[og])      + 0.27f;
    float st = fabsf(SIG[OG + og]) + 0.27f;

    float xf[F_DIM];
    float Sf = 0.0f;
#pragma unroll
    for (int f = 0; f < F_DIM; ++f) {
        float d = ((float)f - mu_f) / sf;
        float e = expf(-0.5f * d * d);
        xf[f] = e;
        Sf += e;
    }
    float xt[T_DIM];
    float St = 0.0f;
#pragma unroll
    for (int t = 0; t < T_DIM; ++t) {
        float d = ((float)t - mu_t) / st;
        float e = expf(-0.5f * d * d);
        xt[t] = e;
        St += e;
    }
    float scale = W[og] / (Sf * St + 1e-7f);
#pragma unroll
    for (int f = 0; f < F_DIM; ++f) Kf[f * OG + og] = xf[f];
#pragma unroll
    for (int t = 0; t < T_DIM; ++t) Kt[og * T_DIM + t] = xt[t] * scale;
}

// ---------------- kernel 1: frequency reduction -> bf16 yf ----------------
// yf[bl][og][tau] = sum_f Kf[f][og] * x[b0+bl][f][tau]   (stored bf16)
__global__ __launch_bounds__(256)
void strf_freq(const float* __restrict__ x,
               const float* __restrict__ Kf,
               ushort16* __restrict__ yf,
               int b0)
{
    const int chunk = blockIdx.x * 256 + threadIdx.x;   // tau/4 chunk, 2000 per row
    const int bl    = blockIdx.y;
    const int og0   = blockIdx.z * 16;
    if (chunk >= T_IN / 4) return;
    const int tau0 = chunk * 4;

    const float* xp = x + (size_t)(b0 + bl) * (F_DIM * T_IN) + tau0;

    float acc[16][4];
#pragma unroll
    for (int i = 0; i < 16; ++i)
#pragma unroll
        for (int j = 0; j < 4; ++j) acc[i][j] = 0.0f;

    float4 cur = *(const float4*)xp;
#pragma unroll 2
    for (int f = 0; f < F_DIM - 1; ++f) {
        float4 nxt = *(const float4*)(xp + (size_t)(f + 1) * T_IN);
        const float* kfp = Kf + f * OG + og0;
        float4 k0 = *(const float4*)(kfp);
        float4 k1 = *(const float4*)(kfp + 4);
        float4 k2 = *(const float4*)(kfp + 8);
        float4 k3 = *(const float4*)(kfp + 12);
        float kv[16] = {k0.x, k0.y, k0.z, k0.w, k1.x, k1.y, k1.z, k1.w,
                        k2.x, k2.y, k2.z, k2.w, k3.x, k3.y, k3.z, k3.w};
        float cv[4] = {cur.x, cur.y, cur.z, cur.w};
#pragma unroll
        for (int i = 0; i < 16; ++i)
#pragma unroll
            for (int j = 0; j < 4; ++j)
                acc[i][j] = fmaf(kv[i], cv[j], acc[i][j]);
        cur = nxt;
    }
    {   // peeled last tap
        const float* kfp = Kf + (F_DIM - 1) * OG + og0;
        float4 k0 = *(const float4*)(kfp);
        float4 k1 = *(const float4*)(kfp + 4);
        float4 k2 = *(const float4*)(kfp + 8);
        float4 k3 = *(const float4*)(kfp + 12);
        float kv[16] = {k0.x, k0.y, k0.z, k0.w, k1.x, k1.y, k1.z, k1.w,
                        k2.x, k2.y, k2.z, k2.w, k3.x, k3.y, k3.z, k3.w};
        float cv[4] = {cur.x, cur.y, cur.z, cur.w};
#pragma unroll
        for (int i = 0; i < 16; ++i)
#pragma unroll
            for (int j = 0; j < 4; ++j)
                acc[i][j] = fmaf(kv[i], cv[j], acc[i][j]);
    }

    ushort16* yp = yf + ((size_t)bl * OG + og0) * T_IN + tau0;
#pragma unroll
    for (int i = 0; i < 16; ++i) {
        ushort4 v;
        v.x = f2bf(acc[i][0]); v.y = f2bf(acc[i][1]);
        v.z = f2bf(acc[i][2]); v.w = f2bf(acc[i][3]);
        *(ushort4*)(yp + (size_t)i * T_IN) = v;   // 8B aligned (tau0 % 4 == 0)
    }
}

// ---------------- kernel 2: LDS-staged 25-tap causal time conv -------------
// block = (seg, o, bl). Stage 4 og rows x (SEG+HALO) bf16 into LDS once;
// each thread emits 8 taus. yf read exactly once overall.
__global__ __launch_bounds__(256)
void strf_time2(const ushort16* __restrict__ yf,
                const float* __restrict__ Kt,
                float* __restrict__ out,
                int b0)
{
    __shared__ __align__(16) ushort16 ys[G_CH * LSTR];

    const int tid = threadIdx.x;
    const int seg = blockIdx.x;            // 0..3
    const int o   = blockIdx.y;            // 0..15
    const int bl  = blockIdx.z;

    // ---- stage: rows og = o*4 .. o*4+3, taus seg*SEG-24 .. seg*SEG+SEG-1 ----
    const ushort16* yg = yf + ((size_t)bl * OG + o * G_CH) * T_IN;
    const int tbase = seg * SEG - HALO;
    for (int e = tid; e < G_CH * LW; e += 256) {
        int r = e / LW;
        int c = e - r * LW;
        int tg = tbase + c;
        ys[r * LSTR + c] = (tg >= 0) ? yg[(size_t)r * T_IN + tg] : (ushort16)0;
    }
    __syncthreads();

    const int chunk = tid;                 // 0..249 used
    if (chunk >= SEG / 8) return;
    const int tau0 = seg * SEG + chunk * 8;

    float acc[8];
#pragma unroll
    for (int j = 0; j < 8; ++j) acc[j] = 0.0f;

#pragma unroll
    for (int g = 0; g < G_CH; ++g) {
        const float* ktp = Kt + (o * G_CH + g) * T_DIM;   // dispatch-uniform
        float kt[T_DIM];
#pragma unroll
        for (int t = 0; t < T_DIM; ++t) kt[t] = ktp[t];

        // window: LDS cols chunk*8 .. chunk*8+31 (= taus tau0-24 .. tau0+7)
        const uint4* p = (const uint4*)&ys[g * LSTR + chunk * 8];  // 16B aligned
        uint4 a = p[0], b = p[1];
        uint32 uw[8] = {a.x, a.y, a.z, a.w, b.x, b.y, b.z, b.w};
        float w[32];
#pragma unroll
        for (int k = 0; k < 8; ++k) {
            w[2 * k + 0] = __uint_as_float(uw[k] << 16);
            w[2 * k + 1] = __uint_as_float(uw[k] & 0xffff0000u);
        }
        // w holds 16 values; need 32 -> second pair of uint4s
        uint4 c2 = p[2], d2 = p[3];
        uint32 uw2[8] = {c2.x, c2.y, c2.z, c2.w, d2.x, d2.y, d2.z, d2.w};
#pragma unroll
        for (int k = 0; k < 8; ++k) {
            w[16 + 2 * k + 0] = __uint_as_float(uw2[k] << 16);
            w[16 + 2 * k + 1] = __uint_as_float(uw2[k] & 0xffff0000u);
        }

#pragma unroll
        for (int t = 0; t < T_DIM; ++t)
#pragma unroll
            for (int j = 0; j < 8; ++j)
                acc[j] = fmaf(kt[t], w[t + j], acc[j]);
    }

    float* op = out + ((size_t)(b0 + bl) * O_CH + o) * T_IN + tau0;
    *(float4*)op       = make_float4(acc[0], acc[1], acc[2], acc[3]);
    *(float4*)(op + 4) = make_float4(acc[4], acc[5], acc[6], acc[7]);
}

// ---------------- fallback: round-2 fused kernel (proven correct) ----------
#define TILE  128
#define EXT   160
#define XSW   168
#define YFW   176

__global__ __launch_bounds__(256, 2)
void strf_main(const float* __restrict__ x,
               const float* __restrict__ Kf,
               const float* __restrict__ Kt,
               float* __restrict__ out)
{
    __shared__ __align__(16) float xs[F_DIM * XSW];
    __shared__ __align__(16) float yfs[OG * YFW];

    const int tid  = threadIdx.x;
    const int tile = blockIdx.x;
    const int b    = blockIdx.y;
    const int t0   = tile * TILE;

    const float* xb = x + (size_t)b * (F_DIM * T_IN);
    for (int idx = tid; idx < F_DIM * EXT; idx += 256) {
        int f = idx / EXT;
        int c = idx - f * EXT;
        int tg = t0 - (T_DIM - 1) + c;
        float v = (tg >= 0 && tg < T_IN) ? xb[f * T_IN + tg] : 0.0f;
        xs[f * XSW + c] = v;
    }
    __syncthreads();

    {
        const int og0  = (tid >> 5) * 8;
        const int tg   = tid & 31;
        const int tau0 = tg * 5;

        float acc[8][5];
#pragma unroll
        for (int i = 0; i < 8; ++i)
#pragma unroll
            for (int j = 0; j < 5; ++j) acc[i][j] = 0.0f;

        const float* kfp = Kf + og0;
        const float* xsp = xs + tau0;
        for (int f = 0; f < F_DIM; ++f) {
            float xv[5];
#pragma unroll
            for (int j = 0; j < 5; ++j) xv[j] = xsp[j];
            xsp += XSW;
            float4 k0 = *(const float4*)(kfp);
            float4 k1 = *(const float4*)(kfp + 4);
            kfp += OG;
            float kf[8] = {k0.x, k0.y, k0.z, k0.w, k1.x, k1.y, k1.z, k1.w};
#pragma unroll
            for (int i = 0; i < 8; ++i)
#pragma unroll
                for (int j = 0; j < 5; ++j)
                    acc[i][j] = fmaf(kf[i], xv[j], acc[i][j]);
        }
#pragma unroll
        for (int i = 0; i < 8; ++i) {
            float* row = yfs + (og0 + i) * YFW;
#pragma unroll
            for (int j = 0; j < 5; ++j) {
                int c  = tau0 + j;
                int pc = c + ((c >> 5) << 2);
                row[pc] = acc[i][j];
            }
        }
    }
    __syncthreads();

    {
        const int o    = tid >> 4;
        const int tg   = tid & 15;
        const int tau0 = tg * 8;

        float acc[8];
#pragma unroll
        for (int j = 0; j < 8; ++j) acc[j] = 0.0f;

        for (int g = 0; g < G_CH; ++g) {
            const int og = o * G_CH + g;
            float kt[T_DIM];
            const float* ktp = Kt + og * T_DIM;
#pragma unroll
            for (int t = 0; t < T_DIM; ++t) kt[t] = ktp[t];

            float w[32];
            const float* row = yfs + og * YFW;
#pragma unroll
            for (int ch = 0; ch < 8; ++ch) {
                int c  = tau0 + ch * 4;
                int pc = c + ((c >> 5) << 2);
                float4 v = *(const float4*)(row + pc);
                w[ch * 4 + 0] = v.x;
                w[ch * 4 + 1] = v.y;
                w[ch * 4 + 2] = v.z;
                w[ch * 4 + 3] = v.w;
            }
#pragma unroll
            for (int t = 0; t < T_DIM; ++t)
#pragma unroll
                for (int j = 0; j < 8; ++j)
                    acc[j] = fmaf(kt[t], w[t + j], acc[j]);
        }

        const int taug = t0 + tau0;
        if (taug + 7 < T_IN) {
            float* op = out + ((size_t)b * O_CH + o) * T_IN + taug;
            *(float4*)op       = make_float4(acc[0], acc[1], acc[2], acc[3]);
            *(float4*)(op + 4) = make_float4(acc[4], acc[5], acc[6], acc[7]);
        }
    }
}

extern "C" void kernel_launch(void* const* d_in, const int* in_sizes, int n_in,
                              void* d_out, int out_size, void* d_ws, size_t ws_size,
                              hipStream_t stream) {
    const float* x   = (const float*)d_in[0];
    const float* W   = (const float*)d_in[1];
    const float* P   = (const float*)d_in[2];
    const float* SIG = (const float*)d_in[3];
    float* outp = (float*)d_out;

    float* Kf = (float*)d_ws;                    // 49*64 floats
    float* Kt = Kf + F_DIM * OG;                 // 64*25 floats

    strf_prep<<<dim3(1), dim3(64), 0, stream>>>(W, P, SIG, Kf, Kt);

    const size_t yf_off_b  = 32768;
    const size_t per_b     = (size_t)OG * T_IN * sizeof(ushort16);  // 1.024 MB / batch
    const size_t avail     = (ws_size > yf_off_b) ? (ws_size - yf_off_b) : 0;
    const int    max_nb    = (int)(avail / per_b);

    if (max_nb >= 8) {
        ushort16* yfp = (ushort16*)((char*)d_ws + yf_off_b);
        for (int b0 = 0; b0 < B_SZ; ) {
            int nb = B_SZ - b0;
            if (nb > max_nb) nb = max_nb;
            // freq: 2000 tau-chunks (of 4) per (b, og-group)
            strf_freq<<<dim3((T_IN / 4 + 255) / 256, nb, G_CH),
                        dim3(256), 0, stream>>>(x, Kf, yfp, b0);
            // time: 4 segments x 16 o per batch
            strf_time2<<<dim3(T_IN / SEG, O_CH, nb),
                         dim3(256), 0, stream>>>(yfp, Kt, outp, b0);
            b0 += nb;
        }
    } else {
        dim3 grid((T_IN + TILE - 1) / TILE, B_SZ);
        strf_main<<<grid, dim3(256), 0, stream>>>(x, Kf, Kt, outp);
    }
}